// Round 6
// baseline (100.967 us; speedup 1.0000x reference)
//
#include <hip/hip_runtime.h>
#include <stdint.h>

typedef _Float16 half8 __attribute__((ext_vector_type(8)));
typedef _Float16 half4 __attribute__((ext_vector_type(4)));
typedef float f32x4 __attribute__((ext_vector_type(4)));

#define MFMA_F16(A, B, C) __builtin_amdgcn_mfma_f32_16x16x32_f16(A, B, C, 0, 0, 0)

#define NN 200000

// RNE float->fp16 x8
__device__ __forceinline__ half8 cvt8(const float* p) {
  half8 a;
#pragma unroll
  for (int e = 0; e < 8; ++e) a[e] = (_Float16)p[e];
  return a;
}

__device__ __forceinline__ void gload_lds16(const void* gp, void* lp) {
  __builtin_amdgcn_global_load_lds(
      (const __attribute__((address_space(1))) uint32_t*)(gp),
      (__attribute__((address_space(3))) uint32_t*)(lp), 16, 0, 0);
}

// ---------------- Kernel 1: encoder  x_enc = fp16(x @ Wenc^T + benc) ----------------
// 128 rows/block, 4 waves (32 rows each, 2 M-tiles). x staged via global_load_lds
// (16 x 1KB outstanding per wave -> in-flight bytes live in LDS, not VGPRs).
// Col-swizzle c ^= (row&7)<<4 applied on the GLOBAL source (linear LDS dest),
// un-applied on the LDS read (involution) -> 4-way max bank aliasing.
__global__ __launch_bounds__(256, 2) void k_enc(const float* __restrict__ x,
                                                const float* __restrict__ Wenc,
                                                const float* __restrict__ benc,
                                                _Float16* __restrict__ xenc) {
  __shared__ float xl[128 * 128];         // 64 KB x tile (row-major, col-swizzled)
  __shared__ _Float16 wlds[16 * 64 * 8];  // 16 KB frag-packed fp16 Wenc

  const int tid = threadIdx.x;
  const int lane = tid & 63, wv = tid >> 6;
  const int r = lane & 15, g = lane >> 4;
  const int base = blockIdx.x * 128;

  // 1) fire 16 direct global->LDS loads (1 KB each); all stay in flight
#pragma unroll
  for (int i = 0; i < 16; ++i) {
    int row = wv * 32 + 2 * i + (lane >> 5);           // tile-local row this lane feeds
    int grow = base + row;
    if (grow >= NN) grow = NN - 1;                     // clamp (stores guarded below)
    int scol = ((lane & 31) * 16) ^ ((row & 7) << 4);  // swizzled source byte-col
    const char* gp = (const char*)(x + (size_t)grow * 128) + scol;
    char* lp = (char*)xl + (wv * 32 + 2 * i) * 512;    // wave-uniform linear dest
    gload_lds16(gp, lp);
  }

  // 2) stage Wenc -> frag-packed fp16 LDS (tiny; overlaps the x-tile in flight)
  for (int i4 = tid; i4 < 2048; i4 += 256) {
    int idx = i4 * 4;
    f32x4 v = *(const f32x4*)(Wenc + idx);
    int j = idx >> 7, k = idx & 127;
    int tile = (j >> 4) * 4 + (k >> 5);
    int ln = ((k >> 3) & 3) * 16 + (j & 15);
    half4 h;
    h[0] = (_Float16)v[0]; h[1] = (_Float16)v[1];
    h[2] = (_Float16)v[2]; h[3] = (_Float16)v[3];
    *(half4*)&wlds[(tile * 64 + ln) * 8 + (k & 7)] = h;
  }

  __syncthreads();  // drains vmcnt (x tile ready) + lgkmcnt, barrier

  // 3) W fragments (A-operand): 16 half8 = 64 VGPR
  half8 W[4][4];
#pragma unroll
  for (int jt = 0; jt < 4; ++jt)
#pragma unroll
    for (int kt = 0; kt < 4; ++kt)
      W[jt][kt] = *(const half8*)&wlds[((jt * 4 + kt) * 64 + lane) * 8];

  // bias per-lane: D row = hid = jt*16 + g*4 + rr
  float bb[4][4];
#pragma unroll
  for (int jt = 0; jt < 4; ++jt)
#pragma unroll
    for (int rr = 0; rr < 4; ++rr) bb[jt][rr] = benc[jt * 16 + g * 4 + rr];

  const int sw = (r & 7) << 4;

#pragma unroll
  for (int mt = 0; mt < 2; ++mt) {
    const int row = wv * 32 + mt * 16 + r;  // row&7 == r&7
    const char* rp = (const char*)xl + row * 512;

    f32x4 acc[4];
#pragma unroll
    for (int jt = 0; jt < 4; ++jt)
      acc[jt] = (f32x4){bb[jt][0], bb[jt][1], bb[jt][2], bb[jt][3]};

#pragma unroll
    for (int kt = 0; kt < 4; ++kt) {
      f32x4 v0 = *(const f32x4*)(rp + ((kt * 128 + g * 32) ^ sw));
      f32x4 v1 = *(const f32x4*)(rp + ((kt * 128 + g * 32 + 16) ^ sw));
      half8 a;
#pragma unroll
      for (int e = 0; e < 4; ++e) {
        a[e] = (_Float16)v0[e];
        a[4 + e] = (_Float16)v1[e];
      }
#pragma unroll
      for (int jt = 0; jt < 4; ++jt)
        acc[jt] = MFMA_F16(W[jt][kt], a, acc[jt]);  // A=W, B=x -> D=[hid][node]
    }

    // D: col = node = r, row = hid = g*4+rr -> one 8B store per jt
    int node = base + wv * 32 + mt * 16 + r;
    if (node < NN) {
#pragma unroll
      for (int jt = 0; jt < 4; ++jt) {
        half4 o;
        o[0] = (_Float16)acc[jt][0]; o[1] = (_Float16)acc[jt][1];
        o[2] = (_Float16)acc[jt][2]; o[3] = (_Float16)acc[jt][3];
        *(half4*)&xenc[(size_t)node * 64 + jt * 16 + g * 4] = o;
      }
    }
  }
}

// ---------------- Kernel 2: GRU over walks + per-graph mean pooling ----------------
// 1 wave = 1 graph = 16 walks. grid 256 x 256thr. All weights in registers.
__global__ __launch_bounds__(256, 1) void k_gru(const _Float16* __restrict__ xenc,
                                                const int* __restrict__ walks,
                                                const float* __restrict__ Wih,
                                                const float* __restrict__ Whh,
                                                const float* __restrict__ bih,
                                                const float* __restrict__ bhh,
                                                float* __restrict__ genc) {
  __shared__ _Float16 h_lds[4][16 * 64];  // per-wave h transpose buffer (8 KB)
  __shared__ int ids[4][256];             // per-wave walk node ids, transposed (4 KB)

  const int tid = threadIdx.x;
  const int lane = tid & 63, wv = tid >> 6;
  const int r = lane & 15, g = lane >> 4;

  // W_ih and W_hh fragments in registers (48 half8 = 192 VGPR), reused 16 steps
  half8 Bih[12][2], Bhh[12][2];
#pragma unroll
  for (int jt = 0; jt < 12; ++jt)
#pragma unroll
    for (int kt = 0; kt < 2; ++kt) {
      Bih[jt][kt] = cvt8(Wih + (jt * 16 + r) * 64 + kt * 32 + g * 8);
      Bhh[jt][kt] = cvt8(Whh + (jt * 16 + r) * 64 + kt * 32 + g * 8);
    }

  // per-lane biases (indexed by output col = jt*16 + r)
  float brz[8], bin4[4], bhn4[4];
#pragma unroll
  for (int jt = 0; jt < 8; ++jt) brz[jt] = bih[jt * 16 + r] + bhh[jt * 16 + r];
#pragma unroll
  for (int jt = 0; jt < 4; ++jt) {
    bin4[jt] = bih[128 + jt * 16 + r];
    bhn4[jt] = bhh[128 + jt * 16 + r];
  }

  const int gph = blockIdx.x * 4 + wv;  // graph id == wave id
  {
    const int* wp = walks + gph * 256;
    int4 v = *(const int4*)(wp + lane * 4);
    int vals[4] = {v.x, v.y, v.z, v.w};
#pragma unroll
    for (int i = 0; i < 4; ++i) {
      int m = lane * 4 + i;  // m = w*16 + t
      ids[wv][(m & 15) * 16 + (m >> 4)] = vals[i];
    }
  }

  for (int i = lane; i < 16 * 64; i += 64) h_lds[wv][i] = (_Float16)0.f;
  // no __syncthreads needed: all LDS traffic is wave-private

  f32x4 h[4];
#pragma unroll
  for (int jt = 0; jt < 4; ++jt) h[jt] = (f32x4){0.f, 0.f, 0.f, 0.f};

  char* hbase = (char*)&h_lds[wv][0];
  const int swz = (r & 7) << 4;

  // prefetch step 0 gather
  int nid0 = ids[wv][r];
  const _Float16* xp0 = xenc + (size_t)nid0 * 64 + g * 8;
  half8 Ax0 = *(const half8*)xp0;
  half8 Ax1 = *(const half8*)(xp0 + 32);

#pragma unroll 2
  for (int t = 0; t < 16; ++t) {
    // prefetch step t+1 gather (ids known upfront; hides L2/L3 latency)
    int tn = (t + 1) & 15;
    int nid = ids[wv][tn * 16 + r];
    const _Float16* xp = xenc + (size_t)nid * 64 + g * 8;
    half8 Nx0 = *(const half8*)xp;
    half8 Nx1 = *(const half8*)(xp + 32);

    // A_h fragments from swizzled LDS (row = walk r)
    half8 Ah0 = *(const half8*)(hbase + ((r * 128 + g * 16) ^ swz));
    half8 Ah1 = *(const half8*)(hbase + ((r * 128 + 64 + g * 16) ^ swz));

    f32x4 aRZ[8], aIN[4], aHN[4];
#pragma unroll
    for (int jt = 0; jt < 8; ++jt) aRZ[jt] = (f32x4){brz[jt], brz[jt], brz[jt], brz[jt]};
#pragma unroll
    for (int jt = 0; jt < 4; ++jt) {
      aIN[jt] = (f32x4){bin4[jt], bin4[jt], bin4[jt], bin4[jt]};
      aHN[jt] = (f32x4){bhn4[jt], bhn4[jt], bhn4[jt], bhn4[jt]};
    }

    // gi = xt @ W_ih^T first (Ax ready from prefetch)
#pragma unroll
    for (int jt = 0; jt < 8; ++jt) {
      aRZ[jt] = MFMA_F16(Ax0, Bih[jt][0], aRZ[jt]);
      aRZ[jt] = MFMA_F16(Ax1, Bih[jt][1], aRZ[jt]);
    }
#pragma unroll
    for (int jt = 0; jt < 4; ++jt) {
      aIN[jt] = MFMA_F16(Ax0, Bih[8 + jt][0], aIN[jt]);
      aIN[jt] = MFMA_F16(Ax1, Bih[8 + jt][1], aIN[jt]);
    }

    // gh = h @ W_hh^T
#pragma unroll
    for (int jt = 0; jt < 8; ++jt) {
      aRZ[jt] = MFMA_F16(Ah0, Bhh[jt][0], aRZ[jt]);
      aRZ[jt] = MFMA_F16(Ah1, Bhh[jt][1], aRZ[jt]);
    }
#pragma unroll
    for (int jt = 0; jt < 4; ++jt) {
      aHN[jt] = MFMA_F16(Ah0, Bhh[8 + jt][0], aHN[jt]);
      aHN[jt] = MFMA_F16(Ah1, Bhh[8 + jt][1], aHN[jt]);
    }

    // gates (division-free: raw v_rcp; tanh = 1 - 2*rcp(e2+1), saturates correctly)
#pragma unroll
    for (int jt = 0; jt < 4; ++jt)
#pragma unroll
      for (int rr = 0; rr < 4; ++rr) {
        float pr = aRZ[jt][rr];
        float pz = aRZ[4 + jt][rr];
        float rg = __builtin_amdgcn_rcpf(1.f + __expf(-pr));
        float zg = __builtin_amdgcn_rcpf(1.f + __expf(-pz));
        float pn = aIN[jt][rr] + rg * aHN[jt][rr];
        float e2 = __expf(2.f * pn);
        float nn = 1.f - 2.f * __builtin_amdgcn_rcpf(e2 + 1.f);
        h[jt][rr] = (1.f - zg) * nn + zg * h[jt][rr];
      }

    // write h (fp16) back to swizzled LDS for next step's A-fragments
    if (t < 15) {
#pragma unroll
      for (int jt = 0; jt < 4; ++jt)
#pragma unroll
        for (int rr = 0; rr < 4; ++rr) {
          int row = g * 4 + rr;
          int byte = (row * 128 + (jt * 16 + r) * 2) ^ ((row & 7) << 4);
          *(_Float16*)(hbase + byte) = (_Float16)h[jt][rr];
        }
    }

    Ax0 = Nx0;
    Ax1 = Nx1;
  }

  // fused segment-mean over the wave's 16 walks
#pragma unroll
  for (int jt = 0; jt < 4; ++jt) {
    float s = h[jt][0] + h[jt][1] + h[jt][2] + h[jt][3];
    s += __shfl_xor(s, 16);
    s += __shfl_xor(s, 32);
    if (g == 0) genc[gph * 64 + jt * 16 + r] = s * 0.0625f;
  }
}

// ---------------- Kernel 3: BN batch stats -> scale/shift ----------------
__global__ __launch_bounds__(1024) void k_stats(const float* __restrict__ genc,
                                                const float* __restrict__ gamma,
                                                const float* __restrict__ beta,
                                                float* __restrict__ ss) {
  __shared__ float sum_s[16][64], sq_s[16][64];
  int j = threadIdx.x & 63, grp = threadIdx.x >> 6;
  float s = 0.f, q = 0.f;
#pragma unroll 4
  for (int rr = 0; rr < 64; ++rr) {
    float v = genc[(grp * 64 + rr) * 64 + j];
    s += v;
    q += v * v;
  }
  sum_s[grp][j] = s;
  sq_s[grp][j] = q;
  __syncthreads();
  if (grp == 0) {
    float S = 0.f, Q = 0.f;
#pragma unroll
    for (int k = 0; k < 16; ++k) {
      S += sum_s[k][j];
      Q += sq_s[k][j];
    }
    float mean = S * (1.f / 1024.f);
    float var = Q * (1.f / 1024.f) - mean * mean;
    float rstd = rsqrtf(var + 1e-5f);
    float sc = gamma[j] * rstd;
    ss[j] = sc;
    ss[64 + j] = beta[j] - mean * sc;
  }
}

// ---------------- Kernel 4: BN apply + MLP + log_softmax ----------------
__global__ __launch_bounds__(256, 1) void k_mlp(const float* __restrict__ genc,
                                                const float* __restrict__ ss,
                                                const float* __restrict__ W1,
                                                const float* __restrict__ b1,
                                                const float* __restrict__ W2,
                                                const float* __restrict__ b2,
                                                float* __restrict__ out) {
  __shared__ float w1[32 * 64], w2[10 * 32], bb1[32], bb2[10], sc[64], sh[64];
  const int tid = threadIdx.x;
  for (int i = tid; i < 32 * 64; i += 256) w1[i] = W1[i];
  for (int i = tid; i < 10 * 32; i += 256) w2[i] = W2[i];
  if (tid < 32) bb1[tid] = b1[tid];
  if (tid >= 32 && tid < 42) bb2[tid - 32] = b2[tid - 32];
  if (tid >= 64 && tid < 128) sc[tid - 64] = ss[tid - 64];
  if (tid >= 128 && tid < 192) sh[tid - 128] = ss[64 + tid - 128];
  __syncthreads();

  const int row = blockIdx.x * 256 + tid;
  float gn[64];
  const f32x4* gp = (const f32x4*)(genc + row * 64);
#pragma unroll
  for (int jq = 0; jq < 16; ++jq) {
    f32x4 v = gp[jq];
#pragma unroll
    for (int e = 0; e < 4; ++e) gn[jq * 4 + e] = v[e] * sc[jq * 4 + e] + sh[jq * 4 + e];
  }

  float h1[32];
#pragma unroll
  for (int i = 0; i < 32; ++i) {
    float a = bb1[i];
#pragma unroll
    for (int j = 0; j < 64; ++j) a += w1[i * 64 + j] * gn[j];
    h1[i] = fmaxf(a, 0.f);
  }

  float lg[10];
  float mx = -1e30f;
#pragma unroll
  for (int c = 0; c < 10; ++c) {
    float a = bb2[c];
#pragma unroll
    for (int i = 0; i < 32; ++i) a += w2[c * 32 + i] * h1[i];
    lg[c] = a;
    mx = fmaxf(mx, a);
  }
  float se = 0.f;
#pragma unroll
  for (int c = 0; c < 10; ++c) se += __expf(lg[c] - mx);
  float lse = mx + __logf(se);
#pragma unroll
  for (int c = 0; c < 10; ++c) out[row * 10 + c] = lg[c] - lse;
}

// ---------------- host launcher ----------------
extern "C" void kernel_launch(void* const* d_in, const int* in_sizes, int n_in,
                              void* d_out, int out_size, void* d_ws, size_t ws_size,
                              hipStream_t stream) {
  const float* x = (const float*)d_in[0];
  const int* walks = (const int*)d_in[1];
  /* d_in[2] walk_batch: repeat(arange(1024),16) -> wave==graph */
  const float* Wenc = (const float*)d_in[3];
  const float* benc = (const float*)d_in[4];
  const float* Wih = (const float*)d_in[5];
  const float* Whh = (const float*)d_in[6];
  const float* bih = (const float*)d_in[7];
  const float* bhh = (const float*)d_in[8];
  const float* gamma = (const float*)d_in[9];
  const float* beta = (const float*)d_in[10];
  const float* W1 = (const float*)d_in[11];
  const float* b1 = (const float*)d_in[12];
  const float* W2 = (const float*)d_in[13];
  const float* b2 = (const float*)d_in[14];
  float* out = (float*)d_out;

  char* ws = (char*)d_ws;
  _Float16* xenc = (_Float16*)ws;                 // 25,600,000 B
  float* genc = (float*)(ws + 25600000);          // 262,144 B
  float* ss = (float*)(ws + 25600000 + 262144);   // 512 B

  k_enc<<<dim3(1563), dim3(256), 0, stream>>>(x, Wenc, benc, xenc);
  k_gru<<<dim3(256), dim3(256), 0, stream>>>(xenc, walks, Wih, Whh, bih, bhh, genc);
  k_stats<<<dim3(1), dim3(1024), 0, stream>>>(genc, gamma, beta, ss);
  k_mlp<<<dim3(4), dim3(256), 0, stream>>>(genc, ss, W1, b1, W2, b2, out);
}

// Round 7
// 85.924 us; speedup vs baseline: 1.1751x; 1.1751x over previous
//
#include <hip/hip_runtime.h>
#include <stdint.h>

typedef _Float16 half8 __attribute__((ext_vector_type(8)));
typedef _Float16 half4 __attribute__((ext_vector_type(4)));
typedef float f32x4 __attribute__((ext_vector_type(4)));

#define MFMA_F16(A, B, C) __builtin_amdgcn_mfma_f32_16x16x32_f16(A, B, C, 0, 0, 0)

#define NN 200000
#define NT 3125     // 200000 / 64 exactly
#define GSTRIDE 512 // k_enc grid

// RNE float->fp16 x8
__device__ __forceinline__ half8 cvt8(const float* p) {
  half8 a;
#pragma unroll
  for (int e = 0; e < 8; ++e) a[e] = (_Float16)p[e];
  return a;
}

__device__ __forceinline__ void gload_lds16(const void* gp, void* lp) {
  __builtin_amdgcn_global_load_lds(
      (const __attribute__((address_space(1))) uint32_t*)(gp),
      (__attribute__((address_space(3))) uint32_t*)(lp), 16, 0, 0);
}

// ---------------- Kernel 1: encoder  x_enc = fp16(x @ Wenc^T + benc) ----------------
// PERSISTENT double-buffered pipeline: 512 blocks (2/CU), 64-row tiles.
// Each wave owns rows [wv*16, wv*16+16) of both buffers -> no in-loop barriers.
// Per iter: issue 8 gload_lds for tile t+512 -> vmcnt(8) (tile t ready, next in
// flight) -> compute/store tile t. Loads continuously outstanding per CU.
__global__ __launch_bounds__(256, 2) void k_enc(const float* __restrict__ x,
                                                const float* __restrict__ Wenc,
                                                const float* __restrict__ benc,
                                                _Float16* __restrict__ xenc) {
  __shared__ float xl[2][64 * 128];       // 2 x 32 KB, col-swizzled rows
  __shared__ _Float16 wlds[16 * 64 * 8];  // 16 KB frag-packed fp16 Wenc

  const int tid = threadIdx.x;
  const int lane = tid & 63, wv = tid >> 6;
  const int r = lane & 15, g = lane >> 4;

  // fire tile t0 loads immediately
  const int t0 = blockIdx.x;
#pragma unroll
  for (int i = 0; i < 8; ++i) {
    int row = wv * 16 + 2 * i + (lane >> 5);
    int grow = t0 * 64 + row;
    if (grow >= NN) grow = NN - 1;
    int scol = ((lane & 31) * 16) ^ ((row & 7) << 4);
    gload_lds16((const char*)(x + (size_t)grow * 128) + scol,
                (char*)&xl[0][0] + (wv * 16 + 2 * i) * 512);
  }

  // stage Wenc -> frag-packed fp16 LDS (overlaps t0 loads)
  for (int i4 = tid; i4 < 2048; i4 += 256) {
    int idx = i4 * 4;
    f32x4 v = *(const f32x4*)(Wenc + idx);
    int j = idx >> 7, k = idx & 127;
    int tile = (j >> 4) * 4 + (k >> 5);
    int ln = ((k >> 3) & 3) * 16 + (j & 15);
    half4 h;
    h[0] = (_Float16)v[0]; h[1] = (_Float16)v[1];
    h[2] = (_Float16)v[2]; h[3] = (_Float16)v[3];
    *(half4*)&wlds[(tile * 64 + ln) * 8 + (k & 7)] = h;
  }
  __syncthreads();  // wlds ready; also drains t0 loads (prologue only)

  // W fragments (A-operand): 16 half8 = 64 VGPR, persistent
  half8 W[4][4];
#pragma unroll
  for (int jt = 0; jt < 4; ++jt)
#pragma unroll
    for (int kt = 0; kt < 4; ++kt)
      W[jt][kt] = *(const half8*)&wlds[((jt * 4 + kt) * 64 + lane) * 8];

  float bb[4][4];
#pragma unroll
  for (int jt = 0; jt < 4; ++jt)
#pragma unroll
    for (int rr = 0; rr < 4; ++rr) bb[jt][rr] = benc[jt * 16 + g * 4 + rr];

  const int sw = (r & 7) << 4;
  int buf = 0;

  for (int t = t0; t < NT; t += GSTRIDE) {
    int tn = t + GSTRIDE;
    if (tn < NT) {
      // issue next tile's loads into the other buffer (this wave's rows only)
#pragma unroll
      for (int i = 0; i < 8; ++i) {
        int row = wv * 16 + 2 * i + (lane >> 5);
        int grow = tn * 64 + row;
        if (grow >= NN) grow = NN - 1;
        int scol = ((lane & 31) * 16) ^ ((row & 7) << 4);
        gload_lds16((const char*)(x + (size_t)grow * 128) + scol,
                    (char*)&xl[buf ^ 1][0] + (wv * 16 + 2 * i) * 512);
      }
      // current tile arrived when only the 8 new loads remain in flight
      asm volatile("s_waitcnt vmcnt(8)" ::: "memory");
    } else {
      asm volatile("s_waitcnt vmcnt(0)" ::: "memory");
    }
    __builtin_amdgcn_sched_barrier(0);

    // compute tile t from xl[buf]
    const char* rp = (const char*)&xl[buf][0] + (wv * 16 + r) * 512;
    f32x4 acc[4];
#pragma unroll
    for (int jt = 0; jt < 4; ++jt)
      acc[jt] = (f32x4){bb[jt][0], bb[jt][1], bb[jt][2], bb[jt][3]};

#pragma unroll
    for (int kt = 0; kt < 4; ++kt) {
      f32x4 v0 = *(const f32x4*)(rp + ((kt * 128 + g * 32) ^ sw));
      f32x4 v1 = *(const f32x4*)(rp + ((kt * 128 + g * 32 + 16) ^ sw));
      half8 a;
#pragma unroll
      for (int e = 0; e < 4; ++e) {
        a[e] = (_Float16)v0[e];
        a[4 + e] = (_Float16)v1[e];
      }
#pragma unroll
      for (int jt = 0; jt < 4; ++jt)
        acc[jt] = MFMA_F16(W[jt][kt], a, acc[jt]);  // D=[hid][node]
    }

    int node = t * 64 + wv * 16 + r;
    if (node < NN) {
#pragma unroll
      for (int jt = 0; jt < 4; ++jt) {
        half4 o;
        o[0] = (_Float16)acc[jt][0]; o[1] = (_Float16)acc[jt][1];
        o[2] = (_Float16)acc[jt][2]; o[3] = (_Float16)acc[jt][3];
        *(half4*)&xenc[(size_t)node * 64 + jt * 16 + g * 4] = o;
      }
    }
    buf ^= 1;
  }
}

// ---------------- Kernel 2: GRU over walks + per-graph mean pooling ----------------
// 1 wave = 1 graph = 16 walks. Weights coalesced-staged via LDS (frag-packed),
// then VGPR-resident. Gather prefetch depth 2.
__global__ __launch_bounds__(256, 1) void k_gru(const _Float16* __restrict__ xenc,
                                                const int* __restrict__ walks,
                                                const float* __restrict__ Wih,
                                                const float* __restrict__ Whh,
                                                const float* __restrict__ bih,
                                                const float* __restrict__ bhh,
                                                float* __restrict__ genc) {
  __shared__ _Float16 wih_lds[24 * 64 * 8];  // 24 KB frag-packed W_ih
  __shared__ _Float16 whh_lds[24 * 64 * 8];  // 24 KB frag-packed W_hh
  __shared__ _Float16 h_lds[4][16 * 64];     // per-wave h transpose buffer
  __shared__ int ids[4][256];                // per-wave walk ids, transposed

  const int tid = threadIdx.x;
  const int lane = tid & 63, wv = tid >> 6;
  const int r = lane & 15, g = lane >> 4;

  // coalesced staging of both weight matrices (R1-verified frag map)
  for (int idx = tid; idx < 192 * 64; idx += 256) {
    int j = idx >> 6, k = idx & 63;
    int tile = (j >> 4) * 2 + (k >> 5);
    int ln = ((k >> 3) & 3) * 16 + (j & 15);
    int off = (tile * 64 + ln) * 8 + (k & 7);
    wih_lds[off] = (_Float16)Wih[idx];
    whh_lds[off] = (_Float16)Whh[idx];
  }

  const int gph = blockIdx.x * 4 + wv;  // graph id == wave id
  {
    const int* wp = walks + gph * 256;
    int4 v = *(const int4*)(wp + lane * 4);
    int vals[4] = {v.x, v.y, v.z, v.w};
#pragma unroll
    for (int i = 0; i < 4; ++i) {
      int m = lane * 4 + i;  // m = w*16 + t
      ids[wv][(m & 15) * 16 + (m >> 4)] = vals[i];
    }
  }
  for (int i = lane; i < 16 * 64; i += 64) h_lds[wv][i] = (_Float16)0.f;

  __syncthreads();

  // weights to VGPR (48 x ds_read_b128)
  half8 Bih[12][2], Bhh[12][2];
#pragma unroll
  for (int jt = 0; jt < 12; ++jt)
#pragma unroll
    for (int kt = 0; kt < 2; ++kt) {
      Bih[jt][kt] = *(const half8*)&wih_lds[((jt * 2 + kt) * 64 + lane) * 8];
      Bhh[jt][kt] = *(const half8*)&whh_lds[((jt * 2 + kt) * 64 + lane) * 8];
    }

  float brz[8], bin4[4], bhn4[4];
#pragma unroll
  for (int jt = 0; jt < 8; ++jt) brz[jt] = bih[jt * 16 + r] + bhh[jt * 16 + r];
#pragma unroll
  for (int jt = 0; jt < 4; ++jt) {
    bin4[jt] = bih[128 + jt * 16 + r];
    bhn4[jt] = bhh[128 + jt * 16 + r];
  }

  f32x4 h[4];
#pragma unroll
  for (int jt = 0; jt < 4; ++jt) h[jt] = (f32x4){0.f, 0.f, 0.f, 0.f};

  char* hbase = (char*)&h_lds[wv][0];
  const int swz = (r & 7) << 4;

  // depth-2 gather prefetch: set A holds step t, set B holds step t+1
  half8 AxA0, AxA1, AxB0, AxB1;
  {
    int n0 = ids[wv][0 * 16 + r];
    const _Float16* p0 = xenc + (size_t)n0 * 64 + g * 8;
    AxA0 = *(const half8*)p0;
    AxA1 = *(const half8*)(p0 + 32);
    int n1 = ids[wv][1 * 16 + r];
    const _Float16* p1 = xenc + (size_t)n1 * 64 + g * 8;
    AxB0 = *(const half8*)p1;
    AxB1 = *(const half8*)(p1 + 32);
  }

#define GRU_STEP(T, AX0, AX1)                                                  \
  {                                                                            \
    half8 Ah0 = *(const half8*)(hbase + ((r * 128 + g * 16) ^ swz));           \
    half8 Ah1 = *(const half8*)(hbase + ((r * 128 + 64 + g * 16) ^ swz));      \
    f32x4 aRZ[8], aIN[4], aHN[4];                                              \
    _Pragma("unroll") for (int jt = 0; jt < 8; ++jt)                           \
        aRZ[jt] = (f32x4){brz[jt], brz[jt], brz[jt], brz[jt]};                 \
    _Pragma("unroll") for (int jt = 0; jt < 4; ++jt) {                         \
      aIN[jt] = (f32x4){bin4[jt], bin4[jt], bin4[jt], bin4[jt]};               \
      aHN[jt] = (f32x4){bhn4[jt], bhn4[jt], bhn4[jt], bhn4[jt]};               \
    }                                                                          \
    _Pragma("unroll") for (int jt = 0; jt < 8; ++jt) {                         \
      aRZ[jt] = MFMA_F16(AX0, Bih[jt][0], aRZ[jt]);                            \
      aRZ[jt] = MFMA_F16(AX1, Bih[jt][1], aRZ[jt]);                            \
    }                                                                          \
    _Pragma("unroll") for (int jt = 0; jt < 4; ++jt) {                         \
      aIN[jt] = MFMA_F16(AX0, Bih[8 + jt][0], aIN[jt]);                        \
      aIN[jt] = MFMA_F16(AX1, Bih[8 + jt][1], aIN[jt]);                        \
    }                                                                          \
    /* prefetch step T+2 into the regs just consumed */                        \
    {                                                                          \
      int nid = ids[wv][(((T) + 2) & 15) * 16 + r];                            \
      const _Float16* xp = xenc + (size_t)nid * 64 + g * 8;                    \
      AX0 = *(const half8*)xp;                                                 \
      AX1 = *(const half8*)(xp + 32);                                          \
    }                                                                          \
    _Pragma("unroll") for (int jt = 0; jt < 8; ++jt) {                         \
      aRZ[jt] = MFMA_F16(Ah0, Bhh[jt][0], aRZ[jt]);                            \
      aRZ[jt] = MFMA_F16(Ah1, Bhh[jt][1], aRZ[jt]);                            \
    }                                                                          \
    _Pragma("unroll") for (int jt = 0; jt < 4; ++jt) {                         \
      aHN[jt] = MFMA_F16(Ah0, Bhh[8 + jt][0], aHN[jt]);                        \
      aHN[jt] = MFMA_F16(Ah1, Bhh[8 + jt][1], aHN[jt]);                        \
    }                                                                          \
    _Pragma("unroll") for (int jt = 0; jt < 4; ++jt)                           \
        _Pragma("unroll") for (int rr = 0; rr < 4; ++rr) {                     \
      float pr = aRZ[jt][rr];                                                  \
      float pz = aRZ[4 + jt][rr];                                              \
      float rg = __builtin_amdgcn_rcpf(1.f + __expf(-pr));                     \
      float zg = __builtin_amdgcn_rcpf(1.f + __expf(-pz));                     \
      float pn = aIN[jt][rr] + rg * aHN[jt][rr];                               \
      float e2 = __expf(2.f * pn);                                             \
      float nn = 1.f - 2.f * __builtin_amdgcn_rcpf(e2 + 1.f);                  \
      h[jt][rr] = (1.f - zg) * nn + zg * h[jt][rr];                            \
    }                                                                          \
    if ((T) < 15) {                                                            \
      _Pragma("unroll") for (int jt = 0; jt < 4; ++jt)                         \
          _Pragma("unroll") for (int rr = 0; rr < 4; ++rr) {                   \
        int row = g * 4 + rr;                                                  \
        int byte = (row * 128 + (jt * 16 + r) * 2) ^ ((row & 7) << 4);         \
        *(_Float16*)(hbase + byte) = (_Float16)h[jt][rr];                      \
      }                                                                        \
    }                                                                          \
  }

  for (int t = 0; t < 16; t += 2) {
    GRU_STEP(t, AxA0, AxA1);
    GRU_STEP(t + 1, AxB0, AxB1);
  }
#undef GRU_STEP

  // fused segment-mean over the wave's 16 walks
#pragma unroll
  for (int jt = 0; jt < 4; ++jt) {
    float s = h[jt][0] + h[jt][1] + h[jt][2] + h[jt][3];
    s += __shfl_xor(s, 16);
    s += __shfl_xor(s, 32);
    if (g == 0) genc[gph * 64 + jt * 16 + r] = s * 0.0625f;
  }
}

// ---------------- Kernel 3: BN batch stats -> scale/shift ----------------
__global__ __launch_bounds__(1024) void k_stats(const float* __restrict__ genc,
                                                const float* __restrict__ gamma,
                                                const float* __restrict__ beta,
                                                float* __restrict__ ss) {
  __shared__ float sum_s[16][64], sq_s[16][64];
  int j = threadIdx.x & 63, grp = threadIdx.x >> 6;
  float s = 0.f, q = 0.f;
#pragma unroll 4
  for (int rr = 0; rr < 64; ++rr) {
    float v = genc[(grp * 64 + rr) * 64 + j];
    s += v;
    q += v * v;
  }
  sum_s[grp][j] = s;
  sq_s[grp][j] = q;
  __syncthreads();
  if (grp == 0) {
    float S = 0.f, Q = 0.f;
#pragma unroll
    for (int k = 0; k < 16; ++k) {
      S += sum_s[k][j];
      Q += sq_s[k][j];
    }
    float mean = S * (1.f / 1024.f);
    float var = Q * (1.f / 1024.f) - mean * mean;
    float rstd = rsqrtf(var + 1e-5f);
    float sc = gamma[j] * rstd;
    ss[j] = sc;
    ss[64 + j] = beta[j] - mean * sc;
  }
}

// ---------------- Kernel 4: BN apply + MLP + log_softmax ----------------
__global__ __launch_bounds__(256, 1) void k_mlp(const float* __restrict__ genc,
                                                const float* __restrict__ ss,
                                                const float* __restrict__ W1,
                                                const float* __restrict__ b1,
                                                const float* __restrict__ W2,
                                                const float* __restrict__ b2,
                                                float* __restrict__ out) {
  __shared__ float w1[32 * 64], w2[10 * 32], bb1[32], bb2[10], sc[64], sh[64];
  const int tid = threadIdx.x;
  for (int i = tid; i < 32 * 64; i += 256) w1[i] = W1[i];
  for (int i = tid; i < 10 * 32; i += 256) w2[i] = W2[i];
  if (tid < 32) bb1[tid] = b1[tid];
  if (tid >= 32 && tid < 42) bb2[tid - 32] = b2[tid - 32];
  if (tid >= 64 && tid < 128) sc[tid - 64] = ss[tid - 64];
  if (tid >= 128 && tid < 192) sh[tid - 128] = ss[64 + tid - 128];
  __syncthreads();

  const int row = blockIdx.x * 256 + tid;
  float gn[64];
  const f32x4* gp = (const f32x4*)(genc + row * 64);
#pragma unroll
  for (int jq = 0; jq < 16; ++jq) {
    f32x4 v = gp[jq];
#pragma unroll
    for (int e = 0; e < 4; ++e) gn[jq * 4 + e] = v[e] * sc[jq * 4 + e] + sh[jq * 4 + e];
  }

  float h1[32];
#pragma unroll
  for (int i = 0; i < 32; ++i) {
    float a = bb1[i];
#pragma unroll
    for (int j = 0; j < 64; ++j) a += w1[i * 64 + j] * gn[j];
    h1[i] = fmaxf(a, 0.f);
  }

  float lg[10];
  float mx = -1e30f;
#pragma unroll
  for (int c = 0; c < 10; ++c) {
    float a = bb2[c];
#pragma unroll
    for (int i = 0; i < 32; ++i) a += w2[c * 32 + i] * h1[i];
    lg[c] = a;
    mx = fmaxf(mx, a);
  }
  float se = 0.f;
#pragma unroll
  for (int c = 0; c < 10; ++c) se += __expf(lg[c] - mx);
  float lse = mx + __logf(se);
#pragma unroll
  for (int c = 0; c < 10; ++c) out[row * 10 + c] = lg[c] - lse;
}

// ---------------- host launcher ----------------
extern "C" void kernel_launch(void* const* d_in, const int* in_sizes, int n_in,
                              void* d_out, int out_size, void* d_ws, size_t ws_size,
                              hipStream_t stream) {
  const float* x = (const float*)d_in[0];
  const int* walks = (const int*)d_in[1];
  /* d_in[2] walk_batch: repeat(arange(1024),16) -> wave==graph */
  const float* Wenc = (const float*)d_in[3];
  const float* benc = (const float*)d_in[4];
  const float* Wih = (const float*)d_in[5];
  const float* Whh = (const float*)d_in[6];
  const float* bih = (const float*)d_in[7];
  const float* bhh = (const float*)d_in[8];
  const float* gamma = (const float*)d_in[9];
  const float* beta = (const float*)d_in[10];
  const float* W1 = (const float*)d_in[11];
  const float* b1 = (const float*)d_in[12];
  const float* W2 = (const float*)d_in[13];
  const float* b2 = (const float*)d_in[14];
  float* out = (float*)d_out;

  char* ws = (char*)d_ws;
  _Float16* xenc = (_Float16*)ws;                 // 25,600,000 B
  float* genc = (float*)(ws + 25600000);          // 262,144 B
  float* ss = (float*)(ws + 25600000 + 262144);   // 512 B

  k_enc<<<dim3(GSTRIDE), dim3(256), 0, stream>>>(x, Wenc, benc, xenc);
  k_gru<<<dim3(256), dim3(256), 0, stream>>>(xenc, walks, Wih, Whh, bih, bhh, genc);
  k_stats<<<dim3(1), dim3(1024), 0, stream>>>(genc, gamma, beta, ss);
  k_mlp<<<dim3(4), dim3(256), 0, stream>>>(genc, ss, W1, b1, W2, b2, out);
}

// Round 8
// 84.041 us; speedup vs baseline: 1.2014x; 1.0224x over previous
//
#include <hip/hip_runtime.h>
#include <stdint.h>

typedef _Float16 half8 __attribute__((ext_vector_type(8)));
typedef _Float16 half4 __attribute__((ext_vector_type(4)));
typedef float f32x4 __attribute__((ext_vector_type(4)));

#define MFMA_F16(A, B, C) __builtin_amdgcn_mfma_f32_16x16x32_f16(A, B, C, 0, 0, 0)

#define NN 200000
#define NT 3125     // 200000 / 64 exactly
#define GSTRIDE 512 // k_enc grid

// RNE float->fp16 x8
__device__ __forceinline__ half8 cvt8(const float* p) {
  half8 a;
#pragma unroll
  for (int e = 0; e < 8; ++e) a[e] = (_Float16)p[e];
  return a;
}

__device__ __forceinline__ void gload_lds16(const void* gp, void* lp) {
  __builtin_amdgcn_global_load_lds(
      (const __attribute__((address_space(1))) uint32_t*)(gp),
      (__attribute__((address_space(3))) uint32_t*)(lp), 16, 0, 0);
}

// ---------------- Kernel 1: encoder  x_enc = fp16(x @ Wenc^T + benc) ----------------
// PERSISTENT double-buffered pipeline: 512 blocks (2/CU), 64-row tiles.
// Each wave owns rows [wv*16, wv*16+16) of both buffers -> no in-loop barriers.
__global__ __launch_bounds__(256, 2) void k_enc(const float* __restrict__ x,
                                                const float* __restrict__ Wenc,
                                                const float* __restrict__ benc,
                                                _Float16* __restrict__ xenc) {
  __shared__ float xl[2][64 * 128];       // 2 x 32 KB, col-swizzled rows
  __shared__ _Float16 wlds[16 * 64 * 8];  // 16 KB frag-packed fp16 Wenc

  const int tid = threadIdx.x;
  const int lane = tid & 63, wv = tid >> 6;
  const int r = lane & 15, g = lane >> 4;

  // fire tile t0 loads immediately
  const int t0 = blockIdx.x;
#pragma unroll
  for (int i = 0; i < 8; ++i) {
    int row = wv * 16 + 2 * i + (lane >> 5);
    int grow = t0 * 64 + row;
    if (grow >= NN) grow = NN - 1;
    int scol = ((lane & 31) * 16) ^ ((row & 7) << 4);
    gload_lds16((const char*)(x + (size_t)grow * 128) + scol,
                (char*)&xl[0][0] + (wv * 16 + 2 * i) * 512);
  }

  // stage Wenc -> frag-packed fp16 LDS (overlaps t0 loads)
  for (int i4 = tid; i4 < 2048; i4 += 256) {
    int idx = i4 * 4;
    f32x4 v = *(const f32x4*)(Wenc + idx);
    int j = idx >> 7, k = idx & 127;
    int tile = (j >> 4) * 4 + (k >> 5);
    int ln = ((k >> 3) & 3) * 16 + (j & 15);
    half4 h;
    h[0] = (_Float16)v[0]; h[1] = (_Float16)v[1];
    h[2] = (_Float16)v[2]; h[3] = (_Float16)v[3];
    *(half4*)&wlds[(tile * 64 + ln) * 8 + (k & 7)] = h;
  }
  __syncthreads();  // wlds ready; also drains t0 loads (prologue only)

  half8 W[4][4];
#pragma unroll
  for (int jt = 0; jt < 4; ++jt)
#pragma unroll
    for (int kt = 0; kt < 4; ++kt)
      W[jt][kt] = *(const half8*)&wlds[((jt * 4 + kt) * 64 + lane) * 8];

  float bb[4][4];
#pragma unroll
  for (int jt = 0; jt < 4; ++jt)
#pragma unroll
    for (int rr = 0; rr < 4; ++rr) bb[jt][rr] = benc[jt * 16 + g * 4 + rr];

  const int sw = (r & 7) << 4;
  int buf = 0;

  for (int t = t0; t < NT; t += GSTRIDE) {
    int tn = t + GSTRIDE;
    if (tn < NT) {
#pragma unroll
      for (int i = 0; i < 8; ++i) {
        int row = wv * 16 + 2 * i + (lane >> 5);
        int grow = tn * 64 + row;
        if (grow >= NN) grow = NN - 1;
        int scol = ((lane & 31) * 16) ^ ((row & 7) << 4);
        gload_lds16((const char*)(x + (size_t)grow * 128) + scol,
                    (char*)&xl[buf ^ 1][0] + (wv * 16 + 2 * i) * 512);
      }
      asm volatile("s_waitcnt vmcnt(8)" ::: "memory");
    } else {
      asm volatile("s_waitcnt vmcnt(0)" ::: "memory");
    }
    __builtin_amdgcn_sched_barrier(0);

    const char* rp = (const char*)&xl[buf][0] + (wv * 16 + r) * 512;
    f32x4 acc[4];
#pragma unroll
    for (int jt = 0; jt < 4; ++jt)
      acc[jt] = (f32x4){bb[jt][0], bb[jt][1], bb[jt][2], bb[jt][3]};

#pragma unroll
    for (int kt = 0; kt < 4; ++kt) {
      f32x4 v0 = *(const f32x4*)(rp + ((kt * 128 + g * 32) ^ sw));
      f32x4 v1 = *(const f32x4*)(rp + ((kt * 128 + g * 32 + 16) ^ sw));
      half8 a;
#pragma unroll
      for (int e = 0; e < 4; ++e) {
        a[e] = (_Float16)v0[e];
        a[4 + e] = (_Float16)v1[e];
      }
#pragma unroll
      for (int jt = 0; jt < 4; ++jt)
        acc[jt] = MFMA_F16(W[jt][kt], a, acc[jt]);  // D=[hid][node]
    }

    int node = t * 64 + wv * 16 + r;
    if (node < NN) {
#pragma unroll
      for (int jt = 0; jt < 4; ++jt) {
        half4 o;
        o[0] = (_Float16)acc[jt][0]; o[1] = (_Float16)acc[jt][1];
        o[2] = (_Float16)acc[jt][2]; o[3] = (_Float16)acc[jt][3];
        *(half4*)&xenc[(size_t)node * 64 + jt * 16 + g * 4] = o;
      }
    }
    buf ^= 1;
  }
}

// ---------------- Kernel 2: GRU over walks + per-graph mean pooling ----------------
// j-SPLIT: 2 waves per graph, each owns 32 of 64 hidden cols (per-wave work
// halves: 24 MFMA, 8 gate-elems/thread). Block = 4 waves = 2 graphs; grid 512
// (2 blocks/CU, 2 waves/SIMD -> TLP overlap of gates vs MFMA). h is shared via
// per-graph DOUBLE-BUFFERED LDS: one __syncthreads per step.
__global__ __launch_bounds__(256, 2) void k_gru(const _Float16* __restrict__ xenc,
                                                const int* __restrict__ walks,
                                                const float* __restrict__ Wih,
                                                const float* __restrict__ Whh,
                                                const float* __restrict__ bih,
                                                const float* __restrict__ bhh,
                                                float* __restrict__ genc) {
  __shared__ _Float16 wih_lds[24 * 64 * 8];  // 24 KB frag-packed W_ih
  __shared__ _Float16 whh_lds[24 * 64 * 8];  // 24 KB frag-packed W_hh
  __shared__ _Float16 h_lds[2][2][16 * 64];  // [graph][buf][16 walks x 64 hid] 8 KB
  __shared__ int ids[2][256];                // per-graph walk ids, transposed

  const int tid = threadIdx.x;
  const int lane = tid & 63, wv = tid >> 6;
  const int r = lane & 15, g = lane >> 4;
  const int p = wv & 1;       // j-half this wave owns
  const int gl = wv >> 1;     // local graph 0/1
  const int gph = blockIdx.x * 2 + gl;

  // coalesced staging of both weight matrices (frag-packed, verified map)
  for (int idx = tid; idx < 192 * 64; idx += 256) {
    int j = idx >> 6, k = idx & 63;
    int tile = (j >> 4) * 2 + (k >> 5);
    int ln = ((k >> 3) & 3) * 16 + (j & 15);
    int off = (tile * 64 + ln) * 8 + (k & 7);
    wih_lds[off] = (_Float16)Wih[idx];
    whh_lds[off] = (_Float16)Whh[idx];
  }

  if (p == 0) {  // one wave per graph stages ids
    const int* wp = walks + gph * 256;
    int4 v = *(const int4*)(wp + lane * 4);
    int vals[4] = {v.x, v.y, v.z, v.w};
#pragma unroll
    for (int i = 0; i < 4; ++i) {
      int m = lane * 4 + i;  // m = w*16 + t
      ids[gl][(m & 15) * 16 + (m >> 4)] = vals[i];
    }
  }

  // zero h buffer 0 of both graphs (h0 = 0)
  for (int i = tid; i < 2048; i += 256)
    ((_Float16*)h_lds)[(i >> 10) * 2048 + (i & 1023)] = (_Float16)0.f;

  __syncthreads();

  // this wave's 12 weight-frag pairs: gate G in {r,z,n}, local jt in {0,1}
  // tile T = G*4 + p*2 + jt  (output col j = T*16 + r)
  half8 Bi[3][2][2], Bh[3][2][2];
#pragma unroll
  for (int G = 0; G < 3; ++G)
#pragma unroll
    for (int jt = 0; jt < 2; ++jt)
#pragma unroll
      for (int kt = 0; kt < 2; ++kt) {
        int T = G * 4 + p * 2 + jt;
        Bi[G][jt][kt] = *(const half8*)&wih_lds[((T * 2 + kt) * 64 + lane) * 8];
        Bh[G][jt][kt] = *(const half8*)&whh_lds[((T * 2 + kt) * 64 + lane) * 8];
      }

  float br[2], bz[2], bin_[2], bhn_[2];
#pragma unroll
  for (int jt = 0; jt < 2; ++jt) {
    int j0 = (p * 2 + jt) * 16 + r;
    br[jt] = bih[j0] + bhh[j0];
    bz[jt] = bih[64 + j0] + bhh[64 + j0];
    bin_[jt] = bih[128 + j0];
    bhn_[jt] = bhh[128 + j0];
  }

  f32x4 h[2];
#pragma unroll
  for (int jt = 0; jt < 2; ++jt) h[jt] = (f32x4){0.f, 0.f, 0.f, 0.f};

  const int swz = (r & 7) << 4;

  // depth-2 gather prefetch (each wave loads full rows; pair duplicates hit L1/L2)
  half8 AxA0, AxA1, AxB0, AxB1;
  {
    int n0 = ids[gl][0 * 16 + r];
    const _Float16* p0 = xenc + (size_t)n0 * 64 + g * 8;
    AxA0 = *(const half8*)p0;
    AxA1 = *(const half8*)(p0 + 32);
    int n1 = ids[gl][1 * 16 + r];
    const _Float16* p1 = xenc + (size_t)n1 * 64 + g * 8;
    AxB0 = *(const half8*)p1;
    AxB1 = *(const half8*)(p1 + 32);
  }

#define GRU_STEP(T, RB, AX0, AX1)                                              \
  {                                                                            \
    char* rbase = (char*)&h_lds[gl][RB][0];                                    \
    char* wbase = (char*)&h_lds[gl][RB ^ 1][0];                                \
    half8 Ah0 = *(const half8*)(rbase + ((r * 128 + g * 16) ^ swz));           \
    half8 Ah1 = *(const half8*)(rbase + ((r * 128 + 64 + g * 16) ^ swz));      \
    f32x4 aR[2], aZ[2], aN[2], aH[2];                                          \
    _Pragma("unroll") for (int jt = 0; jt < 2; ++jt) {                         \
      aR[jt] = (f32x4){br[jt], br[jt], br[jt], br[jt]};                        \
      aZ[jt] = (f32x4){bz[jt], bz[jt], bz[jt], bz[jt]};                        \
      aN[jt] = (f32x4){bin_[jt], bin_[jt], bin_[jt], bin_[jt]};                \
      aH[jt] = (f32x4){bhn_[jt], bhn_[jt], bhn_[jt], bhn_[jt]};                \
    }                                                                          \
    _Pragma("unroll") for (int jt = 0; jt < 2; ++jt) {                         \
      aR[jt] = MFMA_F16(AX0, Bi[0][jt][0], aR[jt]);                            \
      aR[jt] = MFMA_F16(AX1, Bi[0][jt][1], aR[jt]);                            \
      aZ[jt] = MFMA_F16(AX0, Bi[1][jt][0], aZ[jt]);                            \
      aZ[jt] = MFMA_F16(AX1, Bi[1][jt][1], aZ[jt]);                            \
      aN[jt] = MFMA_F16(AX0, Bi[2][jt][0], aN[jt]);                            \
      aN[jt] = MFMA_F16(AX1, Bi[2][jt][1], aN[jt]);                            \
    }                                                                          \
    {                                                                          \
      int nid = ids[gl][(((T) + 2) & 15) * 16 + r];                            \
      const _Float16* xp = xenc + (size_t)nid * 64 + g * 8;                    \
      AX0 = *(const half8*)xp;                                                 \
      AX1 = *(const half8*)(xp + 32);                                          \
    }                                                                          \
    _Pragma("unroll") for (int jt = 0; jt < 2; ++jt) {                         \
      aR[jt] = MFMA_F16(Ah0, Bh[0][jt][0], aR[jt]);                            \
      aR[jt] = MFMA_F16(Ah1, Bh[0][jt][1], aR[jt]);                            \
      aZ[jt] = MFMA_F16(Ah0, Bh[1][jt][0], aZ[jt]);                            \
      aZ[jt] = MFMA_F16(Ah1, Bh[1][jt][1], aZ[jt]);                            \
      aH[jt] = MFMA_F16(Ah0, Bh[2][jt][0], aH[jt]);                            \
      aH[jt] = MFMA_F16(Ah1, Bh[2][jt][1], aH[jt]);                            \
    }                                                                          \
    _Pragma("unroll") for (int jt = 0; jt < 2; ++jt)                           \
        _Pragma("unroll") for (int rr = 0; rr < 4; ++rr) {                     \
      float pr = aR[jt][rr];                                                   \
      float pz = aZ[jt][rr];                                                   \
      float rg = __builtin_amdgcn_rcpf(1.f + __expf(-pr));                     \
      float zg = __builtin_amdgcn_rcpf(1.f + __expf(-pz));                     \
      float pn = aN[jt][rr] + rg * aH[jt][rr];                                 \
      float e2 = __expf(2.f * pn);                                             \
      float nn = 1.f - 2.f * __builtin_amdgcn_rcpf(e2 + 1.f);                  \
      h[jt][rr] = (1.f - zg) * nn + zg * h[jt][rr];                           \
    }                                                                          \
    if ((T) < 15) {                                                            \
      _Pragma("unroll") for (int jt = 0; jt < 2; ++jt)                         \
          _Pragma("unroll") for (int rr = 0; rr < 4; ++rr) {                   \
        int row = g * 4 + rr;                                                  \
        int jg = (p * 2 + jt) * 16 + r;                                        \
        int byte = (row * 128 + jg * 2) ^ ((row & 7) << 4);                    \
        *(_Float16*)(wbase + byte) = (_Float16)h[jt][rr];                      \
      }                                                                        \
    }                                                                          \
    __syncthreads();                                                           \
  }

  for (int t = 0; t < 16; t += 2) {
    GRU_STEP(t, 0, AxA0, AxA1);
    GRU_STEP(t + 1, 1, AxB0, AxB1);
  }
#undef GRU_STEP

  // fused segment-mean over the graph's 16 walks (this wave's 32 cols)
#pragma unroll
  for (int jt = 0; jt < 2; ++jt) {
    float s = h[jt][0] + h[jt][1] + h[jt][2] + h[jt][3];
    s += __shfl_xor(s, 16);
    s += __shfl_xor(s, 32);
    if (g == 0) genc[gph * 64 + (p * 2 + jt) * 16 + r] = s * 0.0625f;
  }
}

// ---------------- Kernel 3: BN batch stats -> scale/shift ----------------
__global__ __launch_bounds__(1024) void k_stats(const float* __restrict__ genc,
                                                const float* __restrict__ gamma,
                                                const float* __restrict__ beta,
                                                float* __restrict__ ss) {
  __shared__ float sum_s[16][64], sq_s[16][64];
  int j = threadIdx.x & 63, grp = threadIdx.x >> 6;
  float s = 0.f, q = 0.f;
#pragma unroll 4
  for (int rr = 0; rr < 64; ++rr) {
    float v = genc[(grp * 64 + rr) * 64 + j];
    s += v;
    q += v * v;
  }
  sum_s[grp][j] = s;
  sq_s[grp][j] = q;
  __syncthreads();
  if (grp == 0) {
    float S = 0.f, Q = 0.f;
#pragma unroll
    for (int k = 0; k < 16; ++k) {
      S += sum_s[k][j];
      Q += sq_s[k][j];
    }
    float mean = S * (1.f / 1024.f);
    float var = Q * (1.f / 1024.f) - mean * mean;
    float rstd = rsqrtf(var + 1e-5f);
    float sc = gamma[j] * rstd;
    ss[j] = sc;
    ss[64 + j] = beta[j] - mean * sc;
  }
}

// ---------------- Kernel 4: BN apply + MLP + log_softmax ----------------
__global__ __launch_bounds__(256, 1) void k_mlp(const float* __restrict__ genc,
                                                const float* __restrict__ ss,
                                                const float* __restrict__ W1,
                                                const float* __restrict__ b1,
                                                const float* __restrict__ W2,
                                                const float* __restrict__ b2,
                                                float* __restrict__ out) {
  __shared__ float w1[32 * 64], w2[10 * 32], bb1[32], bb2[10], sc[64], sh[64];
  const int tid = threadIdx.x;
  for (int i = tid; i < 32 * 64; i += 256) w1[i] = W1[i];
  for (int i = tid; i < 10 * 32; i += 256) w2[i] = W2[i];
  if (tid < 32) bb1[tid] = b1[tid];
  if (tid >= 32 && tid < 42) bb2[tid - 32] = b2[tid - 32];
  if (tid >= 64 && tid < 128) sc[tid - 64] = ss[tid - 64];
  if (tid >= 128 && tid < 192) sh[tid - 128] = ss[64 + tid - 128];
  __syncthreads();

  const int row = blockIdx.x * 256 + tid;
  float gn[64];
  const f32x4* gp = (const f32x4*)(genc + row * 64);
#pragma unroll
  for (int jq = 0; jq < 16; ++jq) {
    f32x4 v = gp[jq];
#pragma unroll
    for (int e = 0; e < 4; ++e) gn[jq * 4 + e] = v[e] * sc[jq * 4 + e] + sh[jq * 4 + e];
  }

  float h1[32];
#pragma unroll
  for (int i = 0; i < 32; ++i) {
    float a = bb1[i];
#pragma unroll
    for (int j = 0; j < 64; ++j) a += w1[i * 64 + j] * gn[j];
    h1[i] = fmaxf(a, 0.f);
  }

  float lg[10];
  float mx = -1e30f;
#pragma unroll
  for (int c = 0; c < 10; ++c) {
    float a = bb2[c];
#pragma unroll
    for (int i = 0; i < 32; ++i) a += w2[c * 32 + i] * h1[i];
    lg[c] = a;
    mx = fmaxf(mx, a);
  }
  float se = 0.f;
#pragma unroll
  for (int c = 0; c < 10; ++c) se += __expf(lg[c] - mx);
  float lse = mx + __logf(se);
#pragma unroll
  for (int c = 0; c < 10; ++c) out[row * 10 + c] = lg[c] - lse;
}

// ---------------- host launcher ----------------
extern "C" void kernel_launch(void* const* d_in, const int* in_sizes, int n_in,
                              void* d_out, int out_size, void* d_ws, size_t ws_size,
                              hipStream_t stream) {
  const float* x = (const float*)d_in[0];
  const int* walks = (const int*)d_in[1];
  /* d_in[2] walk_batch: repeat(arange(1024),16) -> wave-pair==graph */
  const float* Wenc = (const float*)d_in[3];
  const float* benc = (const float*)d_in[4];
  const float* Wih = (const float*)d_in[5];
  const float* Whh = (const float*)d_in[6];
  const float* bih = (const float*)d_in[7];
  const float* bhh = (const float*)d_in[8];
  const float* gamma = (const float*)d_in[9];
  const float* beta = (const float*)d_in[10];
  const float* W1 = (const float*)d_in[11];
  const float* b1 = (const float*)d_in[12];
  const float* W2 = (const float*)d_in[13];
  const float* b2 = (const float*)d_in[14];
  float* out = (float*)d_out;

  char* ws = (char*)d_ws;
  _Float16* xenc = (_Float16*)ws;                 // 25,600,000 B
  float* genc = (float*)(ws + 25600000);          // 262,144 B
  float* ss = (float*)(ws + 25600000 + 262144);   // 512 B

  k_enc<<<dim3(GSTRIDE), dim3(256), 0, stream>>>(x, Wenc, benc, xenc);
  k_gru<<<dim3(512), dim3(256), 0, stream>>>(xenc, walks, Wih, Whh, bih, bhh, genc);
  k_stats<<<dim3(1), dim3(1024), 0, stream>>>(genc, gamma, beta, ss);
  k_mlp<<<dim3(4), dim3(256), 0, stream>>>(genc, ss, W1, b1, W2, b2, out);
}